// Round 11
// baseline (957.441 us; speedup 1.0000x reference)
//
#include <hip/hip_runtime.h>
#include <math.h>

#define T_ 16
#define N_ 20000
#define E_ 320000
#define EN_ (E_ + N_)
#define B_ 16
#define RPF 32
#define RNODES (N_ / RPF)        // 625 nodes per range (exact)
#define SLICE_CAP 12544          // mean 10625, sigma~100 -> +19 sigma headroom
#define BCAP 13000               // fixed bucket capacity (+23 sigma)
#define CPB 64                   // chunks per frame for partition pass
#define CHUNK4 (E_ / 4 / CPB)    // 1250 int4 per chunk
#define BLK2 1250                // blocks per frame for k_agg2

__device__ __forceinline__ float lrelu(float v) { return v >= 0.f ? v : 0.2f * v; }
__device__ __forceinline__ float elu(float v) { return v > 0.f ? v : expm1f(v); }
__device__ __forceinline__ float rdlane(float v, int k) {
    return __uint_as_float(__builtin_amdgcn_readlane(__float_as_uint(v), k));
}

__device__ __forceinline__ void frame_map(int bid, int* frame, int* local) {
    int blk = bid >> 3;
    *frame = (bid & 7) * 2 + (blk & 1);
    *local = blk >> 1;
}

// ---- projected attention vectors: vs1/vd1 (2x7), ws2/wd2 (64) ----
// proj layout: [0..13] vs1[h*7+c], [14..27] vd1, [32..95] ws2, [96..159] wd2
__global__ void k_proj(const float* __restrict__ W1, const float* __restrict__ as1,
                       const float* __restrict__ ad1, const float* __restrict__ W2,
                       const float* __restrict__ as2, const float* __restrict__ ad2,
                       float* __restrict__ proj) {
    int tid = threadIdx.x;
    if (tid < 14) {
        int h = tid / 7, c = tid - h * 7;
        float s = 0.f;
        for (int j = 0; j < 32; ++j) s += W1[c * 64 + h * 32 + j] * as1[h * 32 + j];
        proj[tid] = s;
    } else if (tid < 28) {
        int u = tid - 14, h = u / 7, c = u - h * 7;
        float s = 0.f;
        for (int j = 0; j < 32; ++j) s += W1[c * 64 + h * 32 + j] * ad1[h * 32 + j];
        proj[14 + u] = s;
    } else if (tid >= 32 && tid < 96) {
        int k = tid - 32;
        float s = 0.f;
        for (int j = 0; j < 64; ++j) s += W2[k * 64 + j] * as2[j];
        proj[32 + k] = s;
    } else if (tid >= 96 && tid < 160) {
        int k = tid - 96;
        float s = 0.f;
        for (int j = 0; j < 64; ++j) s += W2[k * 64 + j] * ad2[j];
        proj[96 + k] = s;
    }
}

// ---- partition: per-(frame,chunk) block counts in LDS, reserves runs via one
//      global atomicAdd per range, then scatters packed (dl<<15|src) ----
__global__ __launch_bounds__(256) void k_bfill2(const int* __restrict__ ei,
                                                int* __restrict__ gcur,
                                                int* __restrict__ bucket) {
    int t = blockIdx.x & 15, c = blockIdx.x >> 4;
    __shared__ int cl[RPF];
    __shared__ int rbase[RPF];
    if (threadIdx.x < RPF) cl[threadIdx.x] = 0;
    __syncthreads();
    const int4* db4 = (const int4*)(ei + (size_t)t * 2 * E_ + E_) + c * CHUNK4;
    const int4* sb4 = (const int4*)(ei + (size_t)t * 2 * E_) + c * CHUNK4;
    for (int i = threadIdx.x; i < CHUNK4; i += 256) {
        int4 d = db4[i];
        atomicAdd(&cl[d.x / RNODES], 1);
        atomicAdd(&cl[d.y / RNODES], 1);
        atomicAdd(&cl[d.z / RNODES], 1);
        atomicAdd(&cl[d.w / RNODES], 1);
    }
    __syncthreads();
    if (threadIdx.x < RPF) {
        rbase[threadIdx.x] = atomicAdd(&gcur[t * RPF + threadIdx.x], cl[threadIdx.x]);
        cl[threadIdx.x] = 0;
    }
    __syncthreads();
    for (int i = threadIdx.x; i < CHUNK4; i += 256) {
        int4 d = db4[i];
        int4 s = sb4[i];
        int b, dl, p;
        b = d.x / RNODES; dl = d.x - b * RNODES;
        p = rbase[b] + atomicAdd(&cl[b], 1);
        bucket[(size_t)(t * RPF + b) * BCAP + p] = (dl << 15) | s.x;
        b = d.y / RNODES; dl = d.y - b * RNODES;
        p = rbase[b] + atomicAdd(&cl[b], 1);
        bucket[(size_t)(t * RPF + b) * BCAP + p] = (dl << 15) | s.y;
        b = d.z / RNODES; dl = d.z - b * RNODES;
        p = rbase[b] + atomicAdd(&cl[b], 1);
        bucket[(size_t)(t * RPF + b) * BCAP + p] = (dl << 15) | s.z;
        b = d.w / RNODES; dl = d.w - b * RNODES;
        p = rbase[b] + atomicAdd(&cl[b], 1);
        bucket[(size_t)(t * RPF + b) * BCAP + p] = (dl << 15) | s.w;
    }
}

// ---- per-(frame,range): slice base from shfl-scan of counts; build rowptr
//      span + col slice in LDS; dense flush ----
__global__ __launch_bounds__(256) void k_scat2(const int* __restrict__ bucket,
                                               const int* __restrict__ gcur,
                                               int* __restrict__ rowptr,
                                               int* __restrict__ col) {
    int t = blockIdx.x & 15, rg = blockIdx.x >> 4;
    __shared__ int hist[RNODES];
    __shared__ int cur[RNODES];
    __shared__ int colL[SLICE_CAP];
    __shared__ int wsum[4];
    __shared__ int carryS;
    int tid = threadIdx.x, lane = tid & 63, wv = tid >> 6;
    int vcnt = (lane < RPF) ? gcur[t * RPF + lane] : 0;
    int sc = vcnt;
#pragma unroll
    for (int off = 1; off < RPF; off <<= 1) {
        int u = __shfl_up(sc, off);
        if (lane >= off) sc += u;
    }
    int cnt = __shfl(vcnt, rg);
    int inclAt = __shfl(sc, rg);
    int sliceBase = (inclAt - cnt) + rg * RNODES;
    int r0 = rg * RNODES;
    const int* bk = bucket + (size_t)(t * RPF + rg) * BCAP;
    bool ovf = (cnt + RNODES) > SLICE_CAP;
    int* rp = rowptr + t * (N_ + 1);
    int* cf = col + (size_t)t * EN_;
    for (int i = tid; i < RNODES; i += 256) hist[i] = 0;
    if (tid == 0) carryS = 0;
    __syncthreads();
    for (int i = tid; i < cnt; i += 256) atomicAdd(&hist[bk[i] >> 15], 1);
    __syncthreads();
    for (int base = 0; base < RNODES; base += 256) {
        int i = base + tid;
        int v = (i < RNODES) ? hist[i] + 1 : 0;
        int s = v;
#pragma unroll
        for (int off = 1; off < 64; off <<= 1) {
            int u = __shfl_up(s, off);
            if (lane >= off) s += u;
        }
        if (lane == 63) wsum[wv] = s;
        __syncthreads();
        if (tid == 0) {
            int a = 0;
#pragma unroll
            for (int w2 = 0; w2 < 4; ++w2) { int x2 = wsum[w2]; wsum[w2] = a; a += x2; }
        }
        __syncthreads();
        int incl = s + wsum[wv] + carryS;
        if (i < RNODES) {
            cur[i] = incl - v;
            rp[r0 + i + 1] = sliceBase + incl;
        }
        __syncthreads();
        if (tid == 255) carryS = incl;
        __syncthreads();
    }
    if (rg == 0 && tid == 0) rp[0] = 0;
    __syncthreads();
    for (int i = tid; i < cnt; i += 256) {
        int e = bk[i];
        int dl = e >> 15, src = e & 0x7FFF;
        int p = atomicAdd(&cur[dl], 1);
        if (ovf) cf[sliceBase + p] = src; else colL[p] = src;
    }
    __syncthreads();
    for (int i = tid; i < RNODES; i += 256) {
        int p = cur[i];
        if (ovf) cf[sliceBase + p] = r0 + i; else colL[p] = r0 + i;
    }
    __syncthreads();
    if (!ovf) {
        int len = cnt + RNODES;
        for (int i = tid; i < len; i += 256) cf[sliceBase + i] = colL[i];
    }
}

// ---- layer-1 fused aggregate: gather x[src] (7 floats), on-the-fly attention,
//      post-aggregation W1, bias+ELU, plus layer-2 attention projections ----
__global__ __launch_bounds__(256) void k_agg1(
    const int* __restrict__ rowptr, const int* __restrict__ col,
    const float* __restrict__ x, const float* __restrict__ proj,
    const float* __restrict__ W1, const float* __restrict__ b1,
    float* __restrict__ out1, float* __restrict__ a_s2, float* __restrict__ a_d2) {
    int t, local;
    frame_map(blockIdx.x, &t, &local);
    int lane = threadIdx.x & 63;
    int n = local * 4 + (threadIdx.x >> 6);
    if (n >= N_) return;
    int node = t * N_ + n;
    const float* xb = x + (size_t)t * N_ * 7;
    float vs[14], vd[14];
#pragma unroll
    for (int i = 0; i < 14; ++i) vs[i] = proj[i];
#pragma unroll
    for (int i = 0; i < 14; ++i) vd[i] = proj[14 + i];
    float ad0 = 0.f, ad1 = 0.f;
#pragma unroll
    for (int c = 0; c < 7; ++c) {
        float xc = xb[n * 7 + c];
        ad0 = fmaf(xc, vd[c], ad0);
        ad1 = fmaf(xc, vd[7 + c], ad1);
    }
    int e0 = __builtin_amdgcn_readfirstlane(rowptr[t * (N_ + 1) + n]);
    int e1 = __builtin_amdgcn_readfirstlane(rowptr[t * (N_ + 1) + n + 1]);
    const int* cb = col + (size_t)t * EN_;
    float xa0[7] = {0.f, 0.f, 0.f, 0.f, 0.f, 0.f, 0.f};
    float xa1[7] = {0.f, 0.f, 0.f, 0.f, 0.f, 0.f, 0.f};
    float den0 = 0.f, den1 = 0.f;
    for (int base = e0; base < e1; base += 64) {
        int rem = e1 - base; if (rem > 64) rem = 64;
        if (lane < rem) {
            int s = cb[base + lane];
            float xr[7];
#pragma unroll
            for (int c = 0; c < 7; ++c) xr[c] = xb[s * 7 + c];
            float as0 = 0.f, as1v = 0.f;
#pragma unroll
            for (int c = 0; c < 7; ++c) {
                as0 = fmaf(xr[c], vs[c], as0);
                as1v = fmaf(xr[c], vs[7 + c], as1v);
            }
            float p0 = expf(lrelu(as0 + ad0));
            float p1 = expf(lrelu(as1v + ad1));
            den0 += p0; den1 += p1;
#pragma unroll
            for (int c = 0; c < 7; ++c) {
                xa0[c] = fmaf(p0, xr[c], xa0[c]);
                xa1[c] = fmaf(p1, xr[c], xa1[c]);
            }
        }
    }
#pragma unroll
    for (int m = 1; m < 64; m <<= 1) {
        den0 += __shfl_xor(den0, m);
        den1 += __shfl_xor(den1, m);
#pragma unroll
        for (int c = 0; c < 7; ++c) {
            xa0[c] += __shfl_xor(xa0[c], m);
            xa1[c] += __shfl_xor(xa1[c], m);
        }
    }
    int head = lane >> 5;
    float den = head ? den1 : den0;
    float m_ = 0.f;
#pragma unroll
    for (int c = 0; c < 7; ++c) {
        float xc = head ? xa1[c] : xa0[c];
        m_ = fmaf(xc, W1[c * 64 + lane], m_);
    }
    float o = elu(m_ / (den + 1e-16f) + b1[lane]);
    out1[(size_t)node * 64 + lane] = o;
    float s2 = o * proj[32 + lane], d2 = o * proj[96 + lane];
#pragma unroll
    for (int m = 1; m < 64; m <<= 1) { s2 += __shfl_xor(s2, m); d2 += __shfl_xor(d2, m); }
    if (lane == 0) { a_s2[node] = s2; a_d2[node] = d2; }
}

// ---- layer-2 fused aggregate: gather xin[src], post-aggregation W2 (VGPR),
//      bias+ELU; frame-sequential XCD mapping; grid-stride over nodes ----
__global__ __launch_bounds__(256) void k_agg2(
    const int* __restrict__ rowptr, const int* __restrict__ col,
    const float* __restrict__ a_s, const float* __restrict__ a_d,
    const float* __restrict__ xin, const float* __restrict__ W2,
    const float* __restrict__ b2, float* __restrict__ out2) {
    int bid = blockIdx.x;
    int xcd = bid & 7, blk = bid >> 3;           // blk in [0, 2*BLK2)
    int t = xcd * 2 + (blk >= BLK2 ? 1 : 0);
    int local = (blk >= BLK2) ? blk - BLK2 : blk;
    int lane = threadIdx.x & 63;
    float w2[64];
#pragma unroll
    for (int k = 0; k < 64; ++k) w2[k] = W2[k * 64 + lane];
    float bl = b2[lane];
    const int* cb = col + (size_t)t * EN_;
    const float* hb = xin + (size_t)t * N_ * 64;
    const float* ab = a_s + (size_t)t * N_;
    const float* adb = a_d + (size_t)t * N_;
    const int* rp = rowptr + t * (N_ + 1);
    float* ob = out2 + (size_t)t * N_ * 64;
    for (int n = local * 4 + (threadIdx.x >> 6); n < N_; n += BLK2 * 4) {
        float adv = adb[n];
        int e0 = __builtin_amdgcn_readfirstlane(rp[n]);
        int e1 = __builtin_amdgcn_readfirstlane(rp[n + 1]);
        float acc0 = 0.f, acc1 = 0.f, acc2 = 0.f, acc3 = 0.f, den = 0.f;
        for (int base = e0; base < e1; base += 64) {
            int rem = e1 - base; if (rem > 64) rem = 64;
            int s = 0; float p = 0.f;
            if (lane < rem) {
                s = cb[base + lane];
                p = expf(lrelu(ab[s] + adv));
                den += p;
            }
            int k = 0;
            for (; k + 4 <= rem; k += 4) {
                int sa = __builtin_amdgcn_readlane(s, k);
                int sb = __builtin_amdgcn_readlane(s, k + 1);
                int scx = __builtin_amdgcn_readlane(s, k + 2);
                int sd = __builtin_amdgcn_readlane(s, k + 3);
                float pa = rdlane(p, k), pb = rdlane(p, k + 1);
                float pc = rdlane(p, k + 2), pd = rdlane(p, k + 3);
                acc0 = fmaf(pa, hb[((size_t)sa << 6) + lane], acc0);
                acc1 = fmaf(pb, hb[((size_t)sb << 6) + lane], acc1);
                acc2 = fmaf(pc, hb[((size_t)scx << 6) + lane], acc2);
                acc3 = fmaf(pd, hb[((size_t)sd << 6) + lane], acc3);
            }
            for (; k < rem; ++k) {
                int sa = __builtin_amdgcn_readlane(s, k);
                float pa = rdlane(p, k);
                acc0 = fmaf(pa, hb[((size_t)sa << 6) + lane], acc0);
            }
        }
        float msg = (acc0 + acc1) + (acc2 + acc3);
#pragma unroll
        for (int m = 1; m < 64; m <<= 1) den += __shfl_xor(den, m);
        float hm = 0.f;
#pragma unroll
        for (int k = 0; k < 64; ++k) hm = fmaf(rdlane(msg, k), w2[k], hm);
        ob[(size_t)n * 64 + lane] = elu(hm / (den + 1e-16f) + bl);
    }
}

// ---- sorted-batch mean-pool over activated node features ----
__global__ void k_pool(const float* __restrict__ hact, const int* __restrict__ batch,
                       float* __restrict__ sums, float* __restrict__ cnt) {
    int wid = (blockIdx.x * blockDim.x + threadIdx.x) >> 6;
    int lane = threadIdx.x & 63;
    const int WPF = (N_ + 63) / 64;
    int t = wid / WPF, w = wid - t * WPF;
    if (t >= T_) return;
    int n0 = w * 64, n1 = min(n0 + 64, N_);
    float acc = 0.f, cacc = 0.f;
    int cur_b = batch[t * N_ + n0];
    for (int n = n0; n < n1; ++n) {
        int b = batch[t * N_ + n];
        if (b != cur_b) {
            atomicAdd(&sums[(t * B_ + cur_b) * 64 + lane], acc);
            if (lane == 0) atomicAdd(&cnt[t * B_ + cur_b], cacc);
            acc = 0.f; cacc = 0.f; cur_b = b;
        }
        acc += hact[(size_t)(t * N_ + n) * 64 + lane];
        cacc += 1.f;
    }
    atomicAdd(&sums[(t * B_ + cur_b) * 64 + lane], acc);
    if (lane == 0) atomicAdd(&cnt[t * B_ + cur_b], cacc);
}

__global__ void k_emb(const float* __restrict__ sums, const float* __restrict__ cnt,
                      float* __restrict__ emb) {
    int idx = blockIdx.x * blockDim.x + threadIdx.x;
    if (idx >= T_ * B_ * 64) return;
    emb[idx] = sums[idx] / fmaxf(cnt[idx >> 6], 1.0f);
}

__global__ void k_gx(const float* __restrict__ emb, const float* __restrict__ Wih,
                     const float* __restrict__ bih, float* __restrict__ gx) {
    int idx = blockIdx.x * blockDim.x + threadIdx.x;
    if (idx >= T_ * B_ * 192) return;
    int tb = idx / 192, g = idx - tb * 192;
    const float* er = emb + tb * 64;
    const float* wr = Wih + g * 64;
    float acc = bih[g];
#pragma unroll
    for (int k = 0; k < 64; ++k) acc = fmaf(er[k], wr[k], acc);
    gx[idx] = acc;
}

// ---- sequential GRU + classifier head (single block); Wh padded stride 65 ----
__global__ __launch_bounds__(1024) void k_gru(
    const float* __restrict__ gx_all, const float* __restrict__ Whh,
    const float* __restrict__ bhh, const float* __restrict__ Wc1,
    const float* __restrict__ bc1, const float* __restrict__ Wc2,
    const float* __restrict__ bc2, float* __restrict__ out) {
    __shared__ float Wh[192 * 65];
    __shared__ float hL[16 * 64];
    __shared__ float gh[16 * 192];
    __shared__ float hid[16 * 32];
    int tid = threadIdx.x;
    for (int i = tid; i < 192 * 64; i += 1024) Wh[(i >> 6) * 65 + (i & 63)] = Whh[i];
    hL[tid] = 0.f;
    __syncthreads();
    for (int t = 0; t < T_; ++t) {
        for (int idx = tid; idx < 16 * 192; idx += 1024) {
            int b = idx / 192, g = idx - b * 192;
            float acc = bhh[g];
            const float* wr = Wh + g * 65;
            const float* hr = hL + b * 64;
#pragma unroll
            for (int k = 0; k < 64; ++k) acc = fmaf(hr[k], wr[k], acc);
            gh[idx] = acc;
        }
        __syncthreads();
        const float* gxt = gx_all + t * 16 * 192;
        {
            int b = tid >> 6, c = tid & 63;
            float xr = gxt[b * 192 + c], xz = gxt[b * 192 + 64 + c], xn = gxt[b * 192 + 128 + c];
            float hr_ = gh[b * 192 + c], hz = gh[b * 192 + 64 + c], hn = gh[b * 192 + 128 + c];
            float r = 1.f / (1.f + expf(-(xr + hr_)));
            float z = 1.f / (1.f + expf(-(xz + hz)));
            float n = tanhf(xn + r * hn);
            hL[tid] = (1.f - z) * n + z * hL[tid];
        }
        __syncthreads();
    }
    for (int idx = tid; idx < 16 * 32; idx += 1024) {
        int b = idx >> 5, j = idx & 31;
        float acc = bc1[j];
#pragma unroll
        for (int k = 0; k < 64; ++k) acc = fmaf(hL[b * 64 + k], Wc1[k * 32 + j], acc);
        hid[idx] = fmaxf(acc, 0.f);
    }
    __syncthreads();
    if (tid < 16) {
        float acc = bc2[0];
#pragma unroll
        for (int k = 0; k < 32; ++k) acc = fmaf(hid[tid * 32 + k], Wc2[k], acc);
        out[tid] = acc;
    }
}

extern "C" void kernel_launch(void* const* d_in, const int* in_sizes, int n_in,
                              void* d_out, int out_size, void* d_ws, size_t ws_size,
                              hipStream_t stream) {
    const float* x   = (const float*)d_in[0];
    const int*   ei  = (const int*)d_in[1];
    const int* batch = (const int*)d_in[2];
    const float* W1  = (const float*)d_in[3];
    const float* as1 = (const float*)d_in[4];
    const float* ad1 = (const float*)d_in[5];
    const float* b1  = (const float*)d_in[6];
    const float* W2  = (const float*)d_in[7];
    const float* as2 = (const float*)d_in[8];
    const float* ad2 = (const float*)d_in[9];
    const float* b2  = (const float*)d_in[10];
    const float* Wih = (const float*)d_in[11];
    const float* Whh = (const float*)d_in[12];
    const float* bih = (const float*)d_in[13];
    const float* bhh = (const float*)d_in[14];
    const float* Wc1 = (const float*)d_in[15];
    const float* bc1 = (const float*)d_in[16];
    const float* Wc2 = (const float*)d_in[17];
    const float* bc2 = (const float*)d_in[18];
    float* out = (float*)d_out;

    float* ws = (float*)d_ws;
    float* hX     = ws;                      // 20,480,000 (out1)
    float* hA     = hX + 20480000;           // 20,480,000 (bucket alias / out2)
    float* a_s2   = hA + 20480000;           // 320,000
    float* a_d2   = a_s2 + 320000;           // 320,000
    int*   rowptr = (int*)(a_d2 + 320000);   // 16*(N+1) -> pad 320,032
    int*   col    = rowptr + 320032;         // 16*EN = 5,440,000
    float* sums   = (float*)(col + 5440000); // 16,384
    float* cnt    = sums + 16384;            // 256
    float* emb    = cnt + 256;               // 16,384
    float* gx     = emb + 16384;             // 49,152
    int*   gcur   = (int*)(gx + 49152);      // 512
    float* proj   = (float*)(gcur + 512);    // 256
    int*   bucket = (int*)hA;                // 512*BCAP = 6,656,000 ints

    const int BPF_AGG = (N_ + 3) / 4;        // 5000 (1 node/wave, 4/block)

    hipMemsetAsync(gcur, 0, (size_t)512 * 4, stream);
    hipMemsetAsync(sums, 0, (size_t)(16384 + 256) * 4, stream);

    // ---- CSR build: block-reserved radix partition ----
    k_bfill2<<<16 * CPB, 256, 0, stream>>>(ei, gcur, bucket);
    k_scat2<<<16 * RPF, 256, 0, stream>>>(bucket, gcur, rowptr, col);

    // ---- projections ----
    k_proj<<<1, 256, 0, stream>>>(W1, as1, ad1, W2, as2, ad2, proj);

    // ---- layer 1 (fused attention + aggregate + W1 + ELU + layer-2 projections) ----
    k_agg1<<<16 * BPF_AGG, 256, 0, stream>>>(rowptr, col, x, proj, W1, b1, hX, a_s2, a_d2);

    // ---- layer 2 (fused aggregate + W2 + ELU) ----
    k_agg2<<<16 * BLK2, 256, 0, stream>>>(rowptr, col, a_s2, a_d2, hX, W2, b2, hA);

    // ---- pool + GRU + head ----
    {
        const int WPF = (N_ + 63) / 64;
        int waves = T_ * WPF;
        k_pool<<<(waves * 64 + 255) / 256, 256, 0, stream>>>(hA, batch, sums, cnt);
    }
    k_emb<<<(T_ * B_ * 64 + 255) / 256, 256, 0, stream>>>(sums, cnt, emb);
    k_gx<<<(T_ * B_ * 192 + 255) / 256, 256, 0, stream>>>(emb, Wih, bih, gx);
    k_gru<<<1, 1024, 0, stream>>>(gx, Whh, bhh, Wc1, bc1, Wc2, bc2, out);
}